// Round 1
// baseline (219.616 us; speedup 1.0000x reference)
//
#include <hip/hip_runtime.h>
#include <math.h>

#define SEQ 2048
#define NH 8
#define HD 128
#define DIMF 1024
#define LOG2E 1.4426950408889634f
#define INVTAU 0.08838834764831845f

typedef __attribute__((ext_vector_type(8))) short bf16x8;
typedef __attribute__((ext_vector_type(8))) unsigned short us8;
typedef __attribute__((ext_vector_type(4))) float f32x4;

// persistent scratch (fully rewritten every launch; no stale-state dependence)
__device__ float g_itacc[NH*SEQ];
__device__ float g_ftacc[NH*SEQ];
__device__ float g_aL[NH*SEQ];     // (itilde - csum) * log2e
__device__ float g_cmL[NH*SEQ];    // cummax(a) * log2e
__device__ float g_en[NH*SEQ];     // exp(-(csum + cummax)) = exp(-max_d)
__device__ unsigned short g_Qb[NH*SEQ*HD];  // bf16, [h][s][d]
__device__ unsigned short g_Kb[NH*SEQ*HD];
__device__ unsigned short g_Vb[NH*SEQ*HD];
__device__ unsigned short g_Wb[16*3072];    // bf16, rows 0..7 = Wi, 8..15 = Wf

__device__ __forceinline__ unsigned short f2bf(float x) {
  unsigned u = __float_as_uint(x);
  u += 0x7fffu + ((u >> 16) & 1u);   // RNE
  return (unsigned short)(u >> 16);
}

// ---------------- kernel 1: q/k/v fp32 -> bf16 [h][s][d] ----------------
__global__ __launch_bounds__(256) void convert_kernel(const float* __restrict__ q,
                                                      const float* __restrict__ k,
                                                      const float* __restrict__ v) {
  const int s = blockIdx.x;
  const int t = blockIdx.y;
  const float* src = (t == 0) ? q : (t == 1) ? k : v;
  unsigned short* dst = (t == 0) ? g_Qb : (t == 1) ? g_Kb : g_Vb;
  const int c = threadIdx.x * 4;
  const float4 f = *(const float4*)(src + s*DIMF + c);
  const int h = c >> 7, d = c & 127;
  ushort4 u;
  u.x = f2bf(f.x); u.y = f2bf(f.y); u.z = f2bf(f.z); u.w = f2bf(f.w);
  *(ushort4*)(dst + (h*SEQ + s)*HD + d) = u;
}

// ---------------- kernel 2: Wi/Wf -> bf16 ----------------
__global__ __launch_bounds__(256) void wconv_kernel(const float* __restrict__ Wi,
                                                    const float* __restrict__ Wf) {
  const int gid = blockIdx.x * 256 + threadIdx.x;
  const int e4 = gid * 4;           // 48 blocks * 1024 = 49152 = 16*3072 exactly
  const int p = e4 / 3072;
  const int c = e4 % 3072;
  const float* src = (p < 8) ? (Wi + p*3072 + c) : (Wf + (p-8)*3072 + c);
  const float4 f = *(const float4*)src;
  ushort4 u;
  u.x = f2bf(f.x); u.y = f2bf(f.y); u.z = f2bf(f.z); u.w = f2bf(f.w);
  *(ushort4*)(g_Wb + p*3072 + c) = u;
}

// ---------------- kernel 3: gate projections via MFMA ----------------
// itacc[p][s] = sum_k gate[s][k] * W[p][k]   (M=2048, N=16, K=3072)
__global__ __launch_bounds__(256) void gates_kernel() {
  const int tid = threadIdx.x;
  const int wave = tid >> 6, lane = tid & 63;
  const int q4 = lane >> 4, l16 = lane & 15;
  const int mt = blockIdx.x * 4 + wave;   // 0..127 M-tiles
  const int s0 = mt * 16;
  f32x4 acc = {0.f, 0.f, 0.f, 0.f};
  #pragma unroll 8
  for (int ks = 0; ks < 96; ++ks) {
    const int k0 = ks*32 + q4*8;          // global k of this lane's 8 elems
    const int tsel = k0 >> 10;
    const int rem = k0 & 1023;
    const int hh = rem >> 7, dd = rem & 127;
    const unsigned short* base = (tsel == 0) ? g_Qb : (tsel == 1) ? g_Kb : g_Vb;
    const bf16x8 a = *(const bf16x8*)&base[(hh*SEQ + s0 + l16)*HD + dd];
    const bf16x8 b = *(const bf16x8*)&g_Wb[l16*3072 + k0];
    acc = __builtin_amdgcn_mfma_f32_16x16x32_bf16(a, b, acc, 0, 0, 0);
  }
  #pragma unroll
  for (int r = 0; r < 4; ++r) {
    const int sg = s0 + 4*q4 + r;         // C/D: row = quad*4+reg, col = l16
    if (l16 < 8) g_itacc[l16*SEQ + sg] = acc[r];
    else         g_ftacc[(l16-8)*SEQ + sg] = acc[r];
  }
}

// ---------------- kernel 4: per-head scans ----------------
__global__ __launch_bounds__(64) void scan_kernel(const float* __restrict__ Wi_b,
                                                  const float* __restrict__ Wf_b) {
  const int h = blockIdx.x;
  const int lane = threadIdx.x;
  const float ib = Wi_b[h];
  const float fb = Wf_b[h];
  float coff = 0.f;
  float moff = -__builtin_inff();
  #pragma unroll
  for (int c = 0; c < 32; ++c) {
    const int idx = h*SEQ + c*64 + lane;
    const float ft = g_ftacc[idx] + fb;
    const float ls = fminf(ft, 0.f) - log1pf(expf(-fabsf(ft)));  // logsigmoid
    float x = ls;
    #pragma unroll
    for (int off = 1; off < 64; off <<= 1) {
      const float t = __shfl_up(x, off, 64);
      if (lane >= off) x += t;
    }
    const float csum = coff + x;
    coff += __shfl(x, 63, 64);
    const float a = (g_itacc[idx] + ib) - csum;
    float y = a;
    #pragma unroll
    for (int off = 1; off < 64; off <<= 1) {
      const float t = __shfl_up(y, off, 64);
      if (lane >= off) y = fmaxf(y, t);
    }
    const float cm = fmaxf(moff, y);
    moff = fmaxf(moff, __shfl(y, 63, 64));
    g_aL [idx] = a  * LOG2E;
    g_cmL[idx] = cm * LOG2E;
    g_en [idx] = expf(-(csum + cm));
  }
}

// ---------------- kernel 5: decay attention + normalize + GroupNorm ----------------
// grid.x = head (pins each head's K/V to one XCD L2), grid.y = 64-row i-tile.
// 4 waves in 2x2; QK region/wave = 32x32 (2x2 MFMA tiles); PV region/wave = 32x64 (2x4).
__global__ __launch_bounds__(256, 2) void attn_kernel(const float* __restrict__ gnw,
                                                      const float* __restrict__ gnb,
                                                      float* __restrict__ out) {
  __shared__ __align__(16) unsigned short Qs[64*136];
  __shared__ __align__(16) unsigned short Ks[64*136];
  __shared__ __align__(16) unsigned short Ps[64*72];
  __shared__ __align__(16) unsigned short Vt[128*72];   // V transposed: [d][j]
  __shared__ float Sred[64][2];
  __shared__ float GNs[64][2][2];

  const int h  = blockIdx.x;
  const int i0 = blockIdx.y * 64;
  const int tid = threadIdx.x;
  const int wave = tid >> 6;
  const int lane = tid & 63;
  const int q4 = lane >> 4;
  const int l16 = lane & 15;
  const int wr = wave >> 1;
  const int wc = wave & 1;

  { // stage Q tile 64x128 (bf16 copy, padded stride 136)
    const unsigned short* Qg = g_Qb + (h*SEQ + i0)*HD;
    const int r0 = tid >> 4;
    const int c8 = (tid & 15) * 8;
    #pragma unroll
    for (int i = 0; i < 4; ++i) {
      const int r = r0 + 16*i;
      *(us8*)&Qs[r*136 + c8] = *(const us8*)&Qg[r*HD + c8];
    }
  }

  float cmv[2][4], env[2][4];
  #pragma unroll
  for (int tr = 0; tr < 2; ++tr)
    #pragma unroll
    for (int r = 0; r < 4; ++r) {
      const int rg = i0 + 32*wr + 16*tr + 4*q4 + r;
      cmv[tr][r] = g_cmL[h*SEQ + rg];
      env[tr][r] = g_en [h*SEQ + rg];
    }

  f32x4 accH[2][4];
  float rs[2][4];
  const f32x4 fzero = {0.f, 0.f, 0.f, 0.f};
  #pragma unroll
  for (int tr = 0; tr < 2; ++tr) {
    #pragma unroll
    for (int tc = 0; tc < 4; ++tc) accH[tr][tc] = fzero;
    #pragma unroll
    for (int r = 0; r < 4; ++r) rs[tr][r] = 0.f;
  }

  for (int j0 = 0; j0 <= i0; j0 += 64) {
    __syncthreads();  // previous iter's Ks/Vt/Ps reads complete
    { // stage K tile 64x128
      const unsigned short* Kg = g_Kb + (h*SEQ + j0)*HD;
      const int r0 = tid >> 4;
      const int c8 = (tid & 15) * 8;
      #pragma unroll
      for (int i = 0; i < 4; ++i) {
        const int r = r0 + 16*i;
        *(us8*)&Ks[r*136 + c8] = *(const us8*)&Kg[r*HD + c8];
      }
    }
    { // stage V transposed: Vt[d][j]
      const unsigned short* Vg = g_Vb + (h*SEQ + j0)*HD;
      const int d  = tid >> 1;
      const int jb = (tid & 1) * 32;
      #pragma unroll
      for (int j8 = 0; j8 < 32; j8 += 8) {
        us8 pk;
        #pragma unroll
        for (int m = 0; m < 8; ++m) pk[m] = Vg[(jb + j8 + m)*HD + d];
        *(us8*)&Vt[d*72 + jb + j8] = pk;
      }
    }
    float aLv[2];
    aLv[0] = g_aL[h*SEQ + j0 + 32*wc + l16];
    aLv[1] = g_aL[h*SEQ + j0 + 32*wc + 16 + l16];
    __syncthreads();

    // QK^T: both operands row-major, A-pattern frag loads
    f32x4 c00 = fzero, c01 = fzero, c10 = fzero, c11 = fzero;
    #pragma unroll
    for (int ks = 0; ks < 4; ++ks) {
      const int ko = ks*32 + q4*8;
      const bf16x8 a0 = *(const bf16x8*)&Qs[(32*wr      + l16)*136 + ko];
      const bf16x8 a1 = *(const bf16x8*)&Qs[(32*wr + 16 + l16)*136 + ko];
      const bf16x8 b0 = *(const bf16x8*)&Ks[(32*wc      + l16)*136 + ko];
      const bf16x8 b1 = *(const bf16x8*)&Ks[(32*wc + 16 + l16)*136 + ko];
      c00 = __builtin_amdgcn_mfma_f32_16x16x32_bf16(a0, b0, c00, 0, 0, 0);
      c01 = __builtin_amdgcn_mfma_f32_16x16x32_bf16(a0, b1, c01, 0, 0, 0);
      c10 = __builtin_amdgcn_mfma_f32_16x16x32_bf16(a1, b0, c10, 0, 0, 0);
      c11 = __builtin_amdgcn_mfma_f32_16x16x32_bf16(a1, b1, c11, 0, 0, 0);
    }

    // P = (dot/TAU) * exp(a_j - cmax_i), causal mask on diagonal tile
    const bool diag = (j0 == i0);
    #pragma unroll
    for (int tr = 0; tr < 2; ++tr) {
      #pragma unroll
      for (int tc = 0; tc < 2; ++tc) {
        const f32x4 cc = tr ? (tc ? c11 : c10) : (tc ? c01 : c00);
        const int jg = j0 + 32*wc + 16*tc + l16;
        #pragma unroll
        for (int r = 0; r < 4; ++r) {
          const int rloc = 32*wr + 16*tr + 4*q4 + r;
          const int ig = i0 + rloc;
          const float w = exp2f(aLv[tc] - cmv[tr][r]) * INVTAU;
          float p = cc[r] * w;
          if (diag && (jg > ig)) p = 0.f;
          rs[tr][r] += p;
          Ps[rloc*72 + 32*wc + 16*tc + l16] = f2bf(p);
        }
      }
    }
    __syncthreads();  // Ps complete before PV

    // PV: A = Ps rows, B = Vt rows (= V columns)
    #pragma unroll
    for (int ks = 0; ks < 2; ++ks) {
      const int ko = ks*32 + q4*8;
      const bf16x8 p0 = *(const bf16x8*)&Ps[(32*wr      + l16)*72 + ko];
      const bf16x8 p1 = *(const bf16x8*)&Ps[(32*wr + 16 + l16)*72 + ko];
      #pragma unroll
      for (int tc = 0; tc < 4; ++tc) {
        const bf16x8 vb = *(const bf16x8*)&Vt[(64*wc + 16*tc + l16)*72 + ko];
        accH[0][tc] = __builtin_amdgcn_mfma_f32_16x16x32_bf16(p0, vb, accH[0][tc], 0, 0, 0);
        accH[1][tc] = __builtin_amdgcn_mfma_f32_16x16x32_bf16(p1, vb, accH[1][tc], 0, 0, 0);
      }
    }
  }

  // rowsum reduce across the 16 column-lanes, combine the two wc halves in LDS
  #pragma unroll
  for (int tr = 0; tr < 2; ++tr)
    #pragma unroll
    for (int r = 0; r < 4; ++r) {
      float t = rs[tr][r];
      t += __shfl_xor(t, 1, 16);
      t += __shfl_xor(t, 2, 16);
      t += __shfl_xor(t, 4, 16);
      t += __shfl_xor(t, 8, 16);
      rs[tr][r] = t;
    }
  if (l16 == 0) {
    #pragma unroll
    for (int tr = 0; tr < 2; ++tr)
      #pragma unroll
      for (int r = 0; r < 4; ++r)
        Sred[32*wr + 16*tr + 4*q4 + r][wc] = rs[tr][r];
  }
  __syncthreads();

  float gwv[4], gbv[4];
  #pragma unroll
  for (int tc = 0; tc < 4; ++tc) {
    const int dc = 64*wc + 16*tc + l16;
    gwv[tc] = gnw[h*HD + dc];
    gbv[tc] = gnb[h*HD + dc];
  }

  // normalize by maxit, GroupNorm partials per row
  float sx[2][4], sq[2][4];
  #pragma unroll
  for (int tr = 0; tr < 2; ++tr)
    #pragma unroll
    for (int r = 0; r < 4; ++r) {
      const int rloc = 32*wr + 16*tr + 4*q4 + r;
      const float St = Sred[rloc][0] + Sred[rloc][1];
      const float sc = 1.f / (fmaxf(fabsf(St), env[tr][r]) + 1e-6f);
      float s1 = 0.f, s2 = 0.f;
      #pragma unroll
      for (int tc = 0; tc < 4; ++tc) {
        const float xv = accH[tr][tc][r] * sc;
        accH[tr][tc][r] = xv;
        s1 += xv;
        s2 += xv * xv;
      }
      sx[tr][r] = s1;
      sq[tr][r] = s2;
    }
  #pragma unroll
  for (int tr = 0; tr < 2; ++tr)
    #pragma unroll
    for (int r = 0; r < 4; ++r) {
      float a = sx[tr][r], b = sq[tr][r];
      a += __shfl_xor(a, 1, 16); b += __shfl_xor(b, 1, 16);
      a += __shfl_xor(a, 2, 16); b += __shfl_xor(b, 2, 16);
      a += __shfl_xor(a, 4, 16); b += __shfl_xor(b, 4, 16);
      a += __shfl_xor(a, 8, 16); b += __shfl_xor(b, 8, 16);
      sx[tr][r] = a; sq[tr][r] = b;
    }
  if (l16 == 0) {
    #pragma unroll
    for (int tr = 0; tr < 2; ++tr)
      #pragma unroll
      for (int r = 0; r < 4; ++r) {
        const int rloc = 32*wr + 16*tr + 4*q4 + r;
        GNs[rloc][wc][0] = sx[tr][r];
        GNs[rloc][wc][1] = sq[tr][r];
      }
  }
  __syncthreads();

  #pragma unroll
  for (int tr = 0; tr < 2; ++tr)
    #pragma unroll
    for (int r = 0; r < 4; ++r) {
      const int rloc = 32*wr + 16*tr + 4*q4 + r;
      const float s1 = GNs[rloc][0][0] + GNs[rloc][1][0];
      const float s2 = GNs[rloc][0][1] + GNs[rloc][1][1];
      const float mean = s1 * (1.f/128.f);
      const float var  = s2 * (1.f/128.f) - mean*mean;
      const float rstd = rsqrtf(var + 1e-5f);
      float* op = out + (i0 + rloc)*DIMF + h*HD;
      #pragma unroll
      for (int tc = 0; tc < 4; ++tc) {
        const int dc = 64*wc + 16*tc + l16;
        op[dc] = (accH[tr][tc][r] - mean) * rstd * gwv[tc] + gbv[tc];
      }
    }
}

extern "C" void kernel_launch(void* const* d_in, const int* in_sizes, int n_in,
                              void* d_out, int out_size, void* d_ws, size_t ws_size,
                              hipStream_t stream) {
  (void)in_sizes; (void)n_in; (void)out_size; (void)d_ws; (void)ws_size;
  const float* q    = (const float*)d_in[0];
  const float* k    = (const float*)d_in[1];
  const float* v    = (const float*)d_in[2];
  const float* Wi_w = (const float*)d_in[3];
  const float* Wi_b = (const float*)d_in[4];
  const float* Wf_w = (const float*)d_in[5];
  const float* Wf_b = (const float*)d_in[6];
  const float* gnw  = (const float*)d_in[7];
  const float* gnb  = (const float*)d_in[8];
  float* out = (float*)d_out;

  convert_kernel<<<dim3(SEQ, 3), 256, 0, stream>>>(q, k, v);
  wconv_kernel<<<dim3(48), 256, 0, stream>>>(Wi_w, Wf_w);
  gates_kernel<<<dim3(32), 256, 0, stream>>>();
  scan_kernel<<<dim3(NH), 64, 0, stream>>>(Wi_b, Wf_b);
  attn_kernel<<<dim3(NH, SEQ/64), 256, 0, stream>>>(gnw, gnb, out);
}

// Round 2
// 171.381 us; speedup vs baseline: 1.2815x; 1.2815x over previous
//
#include <hip/hip_runtime.h>
#include <math.h>

#define SEQ 2048
#define NH 8
#define HD 128
#define DIMF 1024
#define LOG2E 1.4426950408889634f
#define INVTAU 0.08838834764831845f

typedef __attribute__((ext_vector_type(8))) short bf16x8;
typedef __attribute__((ext_vector_type(8))) unsigned short us8;
typedef __attribute__((ext_vector_type(4))) float f32x4;

// persistent scratch (fully rewritten every launch; no stale-state dependence)
__device__ float g_itacc[NH*SEQ];
__device__ float g_ftacc[NH*SEQ];
__device__ float g_aL[NH*SEQ];     // (itilde - csum) * log2e
__device__ float g_cmL[NH*SEQ];    // cummax(a) * log2e
__device__ float g_en[NH*SEQ];     // exp(-(csum + cummax)) = exp(-max_d)
__device__ unsigned short g_Qb[NH*SEQ*HD];  // bf16, [h][s][d]
__device__ unsigned short g_Kb[NH*SEQ*HD];
__device__ unsigned short g_Vb[NH*SEQ*HD];
__device__ unsigned short g_Vt[NH*HD*SEQ];  // bf16, [h][d][s]  (V transposed)
__device__ unsigned short g_Wb[16*3072];    // bf16, rows 0..7 = Wi, 8..15 = Wf

__device__ __forceinline__ unsigned short f2bf(float x) {
  unsigned u = __float_as_uint(x);
  u += 0x7fffu + ((u >> 16) & 1u);   // RNE
  return (unsigned short)(u >> 16);
}

// ------- kernel 1: q/k/v fp32 -> bf16 [h][s][d]  +  Wi/Wf -> bf16 (merged) -------
__global__ __launch_bounds__(256) void convert_kernel(const float* __restrict__ q,
                                                      const float* __restrict__ k,
                                                      const float* __restrict__ v,
                                                      const float* __restrict__ Wi,
                                                      const float* __restrict__ Wf) {
  const int bid = blockIdx.x;
  if (bid < 6144) {
    const int s = bid & 2047;
    const int t = bid >> 11;
    const float* src = (t == 0) ? q : (t == 1) ? k : v;
    unsigned short* dst = (t == 0) ? g_Qb : (t == 1) ? g_Kb : g_Vb;
    const int c = threadIdx.x * 4;
    const float4 f = *(const float4*)(src + s*DIMF + c);
    const int h = c >> 7, d = c & 127;
    ushort4 u;
    u.x = f2bf(f.x); u.y = f2bf(f.y); u.z = f2bf(f.z); u.w = f2bf(f.w);
    *(ushort4*)(dst + (h*SEQ + s)*HD + d) = u;
  } else {
    const int gid = (bid - 6144) * 256 + threadIdx.x;
    const int e4 = gid * 4;           // 48 blocks * 1024 = 49152 = 16*3072 exactly
    const int p = e4 / 3072;
    const int c = e4 % 3072;
    const float* src = (p < 8) ? (Wi + p*3072 + c) : (Wf + (p-8)*3072 + c);
    const float4 f = *(const float4*)src;
    ushort4 u;
    u.x = f2bf(f.x); u.y = f2bf(f.y); u.z = f2bf(f.z); u.w = f2bf(f.w);
    *(ushort4*)(g_Wb + p*3072 + c) = u;
  }
}

// ------- kernel 2: V transpose  g_Vb[h][s][d] -> g_Vt[h][d][s] -------
// 64x64 tiles through LDS; conflict-free column gather (lane == d-row).
__global__ __launch_bounds__(256) void vtrans_kernel() {
  __shared__ __align__(16) unsigned short Ts[64*72];
  const int h  = blockIdx.x;
  const int s0 = blockIdx.y * 64;
  const int d0 = blockIdx.z * 64;
  const int t = threadIdx.x;
  { // load 64 s-rows x 64 d-cols, coalesced
    const int sr = t >> 2;
    const int c  = (t & 3) * 16;
    const unsigned short* src = g_Vb + (h*SEQ + s0 + sr)*HD + d0 + c;
    *(us8*)&Ts[sr*72 + c]     = *(const us8*)&src[0];
    *(us8*)&Ts[sr*72 + c + 8] = *(const us8*)&src[8];
  }
  __syncthreads();
  { // store: wave w covers s-cols [w*16,w*16+16), lane l = output d-row
    const int w = t >> 6, l = t & 63;
    unsigned short outv[16];
    #pragma unroll
    for (int j = 0; j < 16; ++j) outv[j] = Ts[(w*16 + j)*72 + l];
    unsigned short* dst = g_Vt + (h*HD + d0 + l)*SEQ + s0 + w*16;
    *(us8*)&dst[0] = *(us8*)&outv[0];
    *(us8*)&dst[8] = *(us8*)&outv[8];
  }
}

// ------- kernel 3: gate projections via MFMA (M=2048, N=16, K=3072) -------
// 128 blocks = one 16-row M-tile each; 4 waves split K, LDS reduce.
__global__ __launch_bounds__(256) void gates_kernel() {
  __shared__ f32x4 red[4][64];
  const int tid = threadIdx.x;
  const int wave = tid >> 6, lane = tid & 63;
  const int q4 = lane >> 4, l16 = lane & 15;
  const int s0 = blockIdx.x * 16;
  f32x4 acc = {0.f, 0.f, 0.f, 0.f};
  #pragma unroll 8
  for (int ks = wave*24; ks < wave*24 + 24; ++ks) {
    const int k0 = ks*32 + q4*8;          // global k of this lane's 8 elems
    const int tsel = k0 >> 10;
    const int rem = k0 & 1023;
    const int hh = rem >> 7, dd = rem & 127;
    const unsigned short* base = (tsel == 0) ? g_Qb : (tsel == 1) ? g_Kb : g_Vb;
    const bf16x8 a = *(const bf16x8*)&base[(hh*SEQ + s0 + l16)*HD + dd];
    const bf16x8 b = *(const bf16x8*)&g_Wb[l16*3072 + k0];
    acc = __builtin_amdgcn_mfma_f32_16x16x32_bf16(a, b, acc, 0, 0, 0);
  }
  red[wave][lane] = acc;
  __syncthreads();
  if (wave == 0) {
    f32x4 s = red[0][lane];
    #pragma unroll
    for (int w = 1; w < 4; ++w) s += red[w][lane];
    #pragma unroll
    for (int r = 0; r < 4; ++r) {
      const int sg = s0 + 4*q4 + r;       // C/D: row = quad*4+reg, col = l16
      if (l16 < 8) g_itacc[l16*SEQ + sg] = s[r];
      else         g_ftacc[(l16-8)*SEQ + sg] = s[r];
    }
  }
}

// ------- kernel 4: per-head scans (block scan, 256 threads, 8 elems/thread) -------
__global__ __launch_bounds__(256) void scan_kernel(const float* __restrict__ Wi_b,
                                                   const float* __restrict__ Wf_b) {
  __shared__ float Wsum[4];
  __shared__ float Wmax[4];
  const int h = blockIdx.x;
  const int t = threadIdx.x;
  const int wave = t >> 6, lane = t & 63;
  const float ib = Wi_b[h];
  const float fb = Wf_b[h];
  const int base = h*SEQ + t*8;

  float it[8], ft[8];
  *(float4*)&it[0] = *(const float4*)&g_itacc[base];
  *(float4*)&it[4] = *(const float4*)&g_itacc[base+4];
  *(float4*)&ft[0] = *(const float4*)&g_ftacc[base];
  *(float4*)&ft[4] = *(const float4*)&g_ftacc[base+4];

  float cs[8];
  float run = 0.f;
  #pragma unroll
  for (int j = 0; j < 8; ++j) {
    const float f = ft[j] + fb;
    const float ls = fminf(f, 0.f) - log1pf(expf(-fabsf(f)));  // logsigmoid
    run += ls;
    cs[j] = run;
  }
  // wave inclusive scan of per-thread sums
  float x = run;
  #pragma unroll
  for (int off = 1; off < 64; off <<= 1) {
    const float tv = __shfl_up(x, off, 64);
    if (lane >= off) x += tv;
  }
  const float wexcl = x - run;
  if (lane == 63) Wsum[wave] = x;
  __syncthreads();
  float boff = 0.f;
  #pragma unroll
  for (int w = 0; w < 4; ++w) if (w < wave) boff += Wsum[w];
  const float cbase = boff + wexcl;

  float a[8], am[8], csum[8];
  float m = -__builtin_inff();
  #pragma unroll
  for (int j = 0; j < 8; ++j) {
    csum[j] = cbase + cs[j];
    a[j] = (it[j] + ib) - csum[j];
    m = fmaxf(m, a[j]);
    am[j] = m;
  }
  // wave inclusive max-scan of per-thread maxes
  float y = m;
  #pragma unroll
  for (int off = 1; off < 64; off <<= 1) {
    const float tv = __shfl_up(y, off, 64);
    if (lane >= off) y = fmaxf(y, tv);
  }
  float e = __shfl_up(y, 1, 64);
  if (lane == 0) e = -__builtin_inff();
  if (lane == 63) Wmax[wave] = y;
  __syncthreads();
  float bmax = -__builtin_inff();
  #pragma unroll
  for (int w = 0; w < 4; ++w) if (w < wave) bmax = fmaxf(bmax, Wmax[w]);
  const float pre = fmaxf(bmax, e);

  float oa[8], ocm[8], oen[8];
  #pragma unroll
  for (int j = 0; j < 8; ++j) {
    const float cm = fmaxf(pre, am[j]);
    oa[j]  = a[j] * LOG2E;
    ocm[j] = cm * LOG2E;
    oen[j] = expf(-(csum[j] + cm));
  }
  *(float4*)&g_aL[base]    = *(float4*)&oa[0];
  *(float4*)&g_aL[base+4]  = *(float4*)&oa[4];
  *(float4*)&g_cmL[base]   = *(float4*)&ocm[0];
  *(float4*)&g_cmL[base+4] = *(float4*)&ocm[4];
  *(float4*)&g_en[base]    = *(float4*)&oen[0];
  *(float4*)&g_en[base+4]  = *(float4*)&oen[4];
}

// ------- kernel 5: decay attention + normalize + GroupNorm -------
// grid.x = head (pins each head's K/V to one XCD L2), grid.y = 64-row i-tile.
// 4 waves in 2x2; QK region/wave = 32x32 (2x2 MFMA tiles); PV region/wave = 32x64 (2x4).
__global__ __launch_bounds__(256, 2) void attn_kernel(const float* __restrict__ gnw,
                                                      const float* __restrict__ gnb,
                                                      float* __restrict__ out) {
  __shared__ __align__(16) unsigned short Qs[64*136];
  __shared__ __align__(16) unsigned short Ks[64*136];
  __shared__ __align__(16) unsigned short Ps[64*72];
  __shared__ __align__(16) unsigned short Vt[128*72];   // V transposed tile: [d][j]
  __shared__ float Sred[64][2];
  __shared__ float GNs[64][2][2];

  const int h  = blockIdx.x;
  const int i0 = blockIdx.y * 64;
  const int tid = threadIdx.x;
  const int wave = tid >> 6;
  const int lane = tid & 63;
  const int q4 = lane >> 4;
  const int l16 = lane & 15;
  const int wr = wave >> 1;
  const int wc = wave & 1;

  { // stage Q tile 64x128 (bf16 copy, padded stride 136)
    const unsigned short* Qg = g_Qb + (h*SEQ + i0)*HD;
    const int r0 = tid >> 4;
    const int c8 = (tid & 15) * 8;
    #pragma unroll
    for (int i = 0; i < 4; ++i) {
      const int r = r0 + 16*i;
      *(us8*)&Qs[r*136 + c8] = *(const us8*)&Qg[r*HD + c8];
    }
  }

  float cmv[2][4], env[2][4];
  #pragma unroll
  for (int tr = 0; tr < 2; ++tr)
    #pragma unroll
    for (int r = 0; r < 4; ++r) {
      const int rg = i0 + 32*wr + 16*tr + 4*q4 + r;
      cmv[tr][r] = g_cmL[h*SEQ + rg];
      env[tr][r] = g_en [h*SEQ + rg];
    }

  f32x4 accH[2][4];
  float rs[2][4];
  const f32x4 fzero = {0.f, 0.f, 0.f, 0.f};
  #pragma unroll
  for (int tr = 0; tr < 2; ++tr) {
    #pragma unroll
    for (int tc = 0; tc < 4; ++tc) accH[tr][tc] = fzero;
    #pragma unroll
    for (int r = 0; r < 4; ++r) rs[tr][r] = 0.f;
  }

  for (int j0 = 0; j0 <= i0; j0 += 64) {
    __syncthreads();  // previous iter's Ks/Vt/Ps reads complete
    { // stage K tile 64x128
      const unsigned short* Kg = g_Kb + (h*SEQ + j0)*HD;
      const int r0 = tid >> 4;
      const int c8 = (tid & 15) * 8;
      #pragma unroll
      for (int i = 0; i < 4; ++i) {
        const int r = r0 + 16*i;
        *(us8*)&Ks[r*136 + c8] = *(const us8*)&Kg[r*HD + c8];
      }
    }
    { // stage Vt tile [128 d][64 j] from pre-transposed g_Vt (coalesced)
      const unsigned short* Vg = g_Vt + h*HD*SEQ + j0;
      const int d = tid >> 1;
      const int c = (tid & 1) * 32;
      *(us8*)&Vt[d*72 + c]      = *(const us8*)&Vg[d*SEQ + c];
      *(us8*)&Vt[d*72 + c + 8]  = *(const us8*)&Vg[d*SEQ + c + 8];
      *(us8*)&Vt[d*72 + c + 16] = *(const us8*)&Vg[d*SEQ + c + 16];
      *(us8*)&Vt[d*72 + c + 24] = *(const us8*)&Vg[d*SEQ + c + 24];
    }
    float aLv[2];
    aLv[0] = g_aL[h*SEQ + j0 + 32*wc + l16];
    aLv[1] = g_aL[h*SEQ + j0 + 32*wc + 16 + l16];
    __syncthreads();

    // QK^T: both operands row-major, A-pattern frag loads
    f32x4 c00 = fzero, c01 = fzero, c10 = fzero, c11 = fzero;
    #pragma unroll
    for (int ks = 0; ks < 4; ++ks) {
      const int ko = ks*32 + q4*8;
      const bf16x8 a0 = *(const bf16x8*)&Qs[(32*wr      + l16)*136 + ko];
      const bf16x8 a1 = *(const bf16x8*)&Qs[(32*wr + 16 + l16)*136 + ko];
      const bf16x8 b0 = *(const bf16x8*)&Ks[(32*wc      + l16)*136 + ko];
      const bf16x8 b1 = *(const bf16x8*)&Ks[(32*wc + 16 + l16)*136 + ko];
      c00 = __builtin_amdgcn_mfma_f32_16x16x32_bf16(a0, b0, c00, 0, 0, 0);
      c01 = __builtin_amdgcn_mfma_f32_16x16x32_bf16(a0, b1, c01, 0, 0, 0);
      c10 = __builtin_amdgcn_mfma_f32_16x16x32_bf16(a1, b0, c10, 0, 0, 0);
      c11 = __builtin_amdgcn_mfma_f32_16x16x32_bf16(a1, b1, c11, 0, 0, 0);
    }

    // P = (dot/TAU) * exp(a_j - cmax_i), causal mask on diagonal tile
    const bool diag = (j0 == i0);
    #pragma unroll
    for (int tr = 0; tr < 2; ++tr) {
      #pragma unroll
      for (int tc = 0; tc < 2; ++tc) {
        const f32x4 cc = tr ? (tc ? c11 : c10) : (tc ? c01 : c00);
        const int jg = j0 + 32*wc + 16*tc + l16;
        #pragma unroll
        for (int r = 0; r < 4; ++r) {
          const int rloc = 32*wr + 16*tr + 4*q4 + r;
          const int ig = i0 + rloc;
          const float w = exp2f(aLv[tc] - cmv[tr][r]) * INVTAU;
          float p = cc[r] * w;
          if (diag && (jg > ig)) p = 0.f;
          rs[tr][r] += p;
          Ps[rloc*72 + 32*wc + 16*tc + l16] = f2bf(p);
        }
      }
    }
    __syncthreads();  // Ps complete before PV

    // PV: A = Ps rows, B = Vt rows (= V columns)
    #pragma unroll
    for (int ks = 0; ks < 2; ++ks) {
      const int ko = ks*32 + q4*8;
      const bf16x8 p0 = *(const bf16x8*)&Ps[(32*wr      + l16)*72 + ko];
      const bf16x8 p1 = *(const bf16x8*)&Ps[(32*wr + 16 + l16)*72 + ko];
      #pragma unroll
      for (int tc = 0; tc < 4; ++tc) {
        const bf16x8 vb = *(const bf16x8*)&Vt[(64*wc + 16*tc + l16)*72 + ko];
        accH[0][tc] = __builtin_amdgcn_mfma_f32_16x16x32_bf16(p0, vb, accH[0][tc], 0, 0, 0);
        accH[1][tc] = __builtin_amdgcn_mfma_f32_16x16x32_bf16(p1, vb, accH[1][tc], 0, 0, 0);
      }
    }
  }

  // rowsum reduce across the 16 column-lanes, combine the two wc halves in LDS
  #pragma unroll
  for (int tr = 0; tr < 2; ++tr)
    #pragma unroll
    for (int r = 0; r < 4; ++r) {
      float t = rs[tr][r];
      t += __shfl_xor(t, 1, 16);
      t += __shfl_xor(t, 2, 16);
      t += __shfl_xor(t, 4, 16);
      t += __shfl_xor(t, 8, 16);
      rs[tr][r] = t;
    }
  if (l16 == 0) {
    #pragma unroll
    for (int tr = 0; tr < 2; ++tr)
      #pragma unroll
      for (int r = 0; r < 4; ++r)
        Sred[32*wr + 16*tr + 4*q4 + r][wc] = rs[tr][r];
  }
  __syncthreads();

  float gwv[4], gbv[4];
  #pragma unroll
  for (int tc = 0; tc < 4; ++tc) {
    const int dc = 64*wc + 16*tc + l16;
    gwv[tc] = gnw[h*HD + dc];
    gbv[tc] = gnb[h*HD + dc];
  }

  // normalize by maxit, GroupNorm partials per row
  float sx[2][4], sq[2][4];
  #pragma unroll
  for (int tr = 0; tr < 2; ++tr)
    #pragma unroll
    for (int r = 0; r < 4; ++r) {
      const int rloc = 32*wr + 16*tr + 4*q4 + r;
      const float St = Sred[rloc][0] + Sred[rloc][1];
      const float sc = 1.f / (fmaxf(fabsf(St), env[tr][r]) + 1e-6f);
      float s1 = 0.f, s2 = 0.f;
      #pragma unroll
      for (int tc = 0; tc < 4; ++tc) {
        const float xv = accH[tr][tc][r] * sc;
        accH[tr][tc][r] = xv;
        s1 += xv;
        s2 += xv * xv;
      }
      sx[tr][r] = s1;
      sq[tr][r] = s2;
    }
  #pragma unroll
  for (int tr = 0; tr < 2; ++tr)
    #pragma unroll
    for (int r = 0; r < 4; ++r) {
      float a = sx[tr][r], b = sq[tr][r];
      a += __shfl_xor(a, 1, 16); b += __shfl_xor(b, 1, 16);
      a += __shfl_xor(a, 2, 16); b += __shfl_xor(b, 2, 16);
      a += __shfl_xor(a, 4, 16); b += __shfl_xor(b, 4, 16);
      a += __shfl_xor(a, 8, 16); b += __shfl_xor(b, 8, 16);
      sx[tr][r] = a; sq[tr][r] = b;
    }
  if (l16 == 0) {
    #pragma unroll
    for (int tr = 0; tr < 2; ++tr)
      #pragma unroll
      for (int r = 0; r < 4; ++r) {
        const int rloc = 32*wr + 16*tr + 4*q4 + r;
        GNs[rloc][wc][0] = sx[tr][r];
        GNs[rloc][wc][1] = sq[tr][r];
      }
  }
  __syncthreads();

  #pragma unroll
  for (int tr = 0; tr < 2; ++tr)
    #pragma unroll
    for (int r = 0; r < 4; ++r) {
      const int rloc = 32*wr + 16*tr + 4*q4 + r;
      const float s1 = GNs[rloc][0][0] + GNs[rloc][1][0];
      const float s2 = GNs[rloc][0][1] + GNs[rloc][1][1];
      const float mean = s1 * (1.f/128.f);
      const float var  = s2 * (1.f/128.f) - mean*mean;
      const float rstd = rsqrtf(var + 1e-5f);
      float* op = out + (i0 + rloc)*DIMF + h*HD;
      #pragma unroll
      for (int tc = 0; tc < 4; ++tc) {
        const int dc = 64*wc + 16*tc + l16;
        op[dc] = (accH[tr][tc][r] - mean) * rstd * gwv[tc] + gbv[tc];
      }
    }
}

extern "C" void kernel_launch(void* const* d_in, const int* in_sizes, int n_in,
                              void* d_out, int out_size, void* d_ws, size_t ws_size,
                              hipStream_t stream) {
  (void)in_sizes; (void)n_in; (void)out_size; (void)d_ws; (void)ws_size;
  const float* q    = (const float*)d_in[0];
  const float* k    = (const float*)d_in[1];
  const float* v    = (const float*)d_in[2];
  const float* Wi_w = (const float*)d_in[3];
  const float* Wi_b = (const float*)d_in[4];
  const float* Wf_w = (const float*)d_in[5];
  const float* Wf_b = (const float*)d_in[6];
  const float* gnw  = (const float*)d_in[7];
  const float* gnb  = (const float*)d_in[8];
  float* out = (float*)d_out;

  convert_kernel<<<dim3(6192), 256, 0, stream>>>(q, k, v, Wi_w, Wf_w);
  vtrans_kernel<<<dim3(NH, SEQ/64, HD/64), 256, 0, stream>>>();
  gates_kernel<<<dim3(128), 256, 0, stream>>>();
  scan_kernel<<<dim3(NH), 256, 0, stream>>>(Wi_b, Wf_b);
  attn_kernel<<<dim3(NH, SEQ/64), 256, 0, stream>>>(gnw, gnb, out);
}

// Round 3
// 159.062 us; speedup vs baseline: 1.3807x; 1.0774x over previous
//
#include <hip/hip_runtime.h>
#include <math.h>

#define SEQ 2048
#define NH 8
#define HD 128
#define DIMF 1024
#define LOG2E 1.4426950408889634f
#define INVTAU 0.08838834764831845f

typedef __attribute__((ext_vector_type(8))) short bf16x8;
typedef __attribute__((ext_vector_type(8))) unsigned short us8;
typedef __attribute__((ext_vector_type(4))) float f32x4;

// persistent scratch (fully rewritten every launch; no stale-state dependence)
__device__ float g_itacc[NH*SEQ];
__device__ float g_ftacc[NH*SEQ];
__device__ float g_aL[NH*SEQ];     // (itilde - csum) * log2e
__device__ float g_cmL[NH*SEQ];    // cummax(a) * log2e
__device__ float g_en[NH*SEQ];     // exp(-(csum + cummax)) = exp(-max_d)
__device__ unsigned short g_Qb[NH*SEQ*HD];  // bf16, [h][s][d]
__device__ unsigned short g_Kb[NH*SEQ*HD];
__device__ unsigned short g_Vb[NH*SEQ*HD];
__device__ unsigned short g_Vt[NH*HD*SEQ];  // bf16, [h][d][s]  (V transposed)
__device__ unsigned short g_Wb[16*3072];    // bf16, rows 0..7 = Wi, 8..15 = Wf
// j-chunk partials: 640 slots (8 heads x 80 chunk-slots)
__device__ float g_Opart[640*64*128];       // fp32 partial O tiles
__device__ float g_Spart[640*64];           // fp32 partial rowsums

__device__ __forceinline__ unsigned short f2bf(float x) {
  unsigned u = __float_as_uint(x);
  u += 0x7fffu + ((u >> 16) & 1u);   // RNE
  return (unsigned short)(u >> 16);
}

// ------- kernel 1: q/k/v fp32 -> bf16 [h][s][d]  +  Wi/Wf -> bf16 (merged) -------
__global__ __launch_bounds__(256) void convert_kernel(const float* __restrict__ q,
                                                      const float* __restrict__ k,
                                                      const float* __restrict__ v,
                                                      const float* __restrict__ Wi,
                                                      const float* __restrict__ Wf) {
  const int bid = blockIdx.x;
  if (bid < 6144) {
    const int s = bid & 2047;
    const int t = bid >> 11;
    const float* src = (t == 0) ? q : (t == 1) ? k : v;
    unsigned short* dst = (t == 0) ? g_Qb : (t == 1) ? g_Kb : g_Vb;
    const int c = threadIdx.x * 4;
    const float4 f = *(const float4*)(src + s*DIMF + c);
    const int h = c >> 7, d = c & 127;
    ushort4 u;
    u.x = f2bf(f.x); u.y = f2bf(f.y); u.z = f2bf(f.z); u.w = f2bf(f.w);
    *(ushort4*)(dst + (h*SEQ + s)*HD + d) = u;
  } else {
    const int gid = (bid - 6144) * 256 + threadIdx.x;
    const int e4 = gid * 4;           // 48 blocks * 1024 = 49152 = 16*3072 exactly
    const int p = e4 / 3072;
    const int c = e4 % 3072;
    const float* src = (p < 8) ? (Wi + p*3072 + c) : (Wf + (p-8)*3072 + c);
    const float4 f = *(const float4*)src;
    ushort4 u;
    u.x = f2bf(f.x); u.y = f2bf(f.y); u.z = f2bf(f.z); u.w = f2bf(f.w);
    *(ushort4*)(g_Wb + p*3072 + c) = u;
  }
}

// ------- kernel 2: V transpose  g_Vb[h][s][d] -> g_Vt[h][d][s] -------
__global__ __launch_bounds__(256) void vtrans_kernel() {
  __shared__ __align__(16) unsigned short Ts[64*72];
  const int h  = blockIdx.x;
  const int s0 = blockIdx.y * 64;
  const int d0 = blockIdx.z * 64;
  const int t = threadIdx.x;
  { // load 64 s-rows x 64 d-cols, coalesced
    const int sr = t >> 2;
    const int c  = (t & 3) * 16;
    const unsigned short* src = g_Vb + (h*SEQ + s0 + sr)*HD + d0 + c;
    *(us8*)&Ts[sr*72 + c]     = *(const us8*)&src[0];
    *(us8*)&Ts[sr*72 + c + 8] = *(const us8*)&src[8];
  }
  __syncthreads();
  { // store: wave w covers s-cols [w*16,w*16+16), lane l = output d-row
    const int w = t >> 6, l = t & 63;
    unsigned short outv[16];
    #pragma unroll
    for (int j = 0; j < 16; ++j) outv[j] = Ts[(w*16 + j)*72 + l];
    unsigned short* dst = g_Vt + (h*HD + d0 + l)*SEQ + s0 + w*16;
    *(us8*)&dst[0] = *(us8*)&outv[0];
    *(us8*)&dst[8] = *(us8*)&outv[8];
  }
}

// ------- kernel 3: gate projections via MFMA (M=2048, N=16, K=3072) -------
__global__ __launch_bounds__(256) void gates_kernel() {
  __shared__ f32x4 red[4][64];
  const int tid = threadIdx.x;
  const int wave = tid >> 6, lane = tid & 63;
  const int q4 = lane >> 4, l16 = lane & 15;
  const int s0 = blockIdx.x * 16;
  f32x4 acc = {0.f, 0.f, 0.f, 0.f};
  #pragma unroll 8
  for (int ks = wave*24; ks < wave*24 + 24; ++ks) {
    const int k0 = ks*32 + q4*8;          // global k of this lane's 8 elems
    const int tsel = k0 >> 10;
    const int rem = k0 & 1023;
    const int hh = rem >> 7, dd = rem & 127;
    const unsigned short* base = (tsel == 0) ? g_Qb : (tsel == 1) ? g_Kb : g_Vb;
    const bf16x8 a = *(const bf16x8*)&base[(hh*SEQ + s0 + l16)*HD + dd];
    const bf16x8 b = *(const bf16x8*)&g_Wb[l16*3072 + k0];
    acc = __builtin_amdgcn_mfma_f32_16x16x32_bf16(a, b, acc, 0, 0, 0);
  }
  red[wave][lane] = acc;
  __syncthreads();
  if (wave == 0) {
    f32x4 s = red[0][lane];
    #pragma unroll
    for (int w = 1; w < 4; ++w) s += red[w][lane];
    #pragma unroll
    for (int r = 0; r < 4; ++r) {
      const int sg = s0 + 4*q4 + r;       // C/D: row = quad*4+reg, col = l16
      if (l16 < 8) g_itacc[l16*SEQ + sg] = s[r];
      else         g_ftacc[(l16-8)*SEQ + sg] = s[r];
    }
  }
}

// ------- kernel 4: per-head scans (block scan, 256 threads, 8 elems/thread) -------
__global__ __launch_bounds__(256) void scan_kernel(const float* __restrict__ Wi_b,
                                                   const float* __restrict__ Wf_b) {
  __shared__ float Wsum[4];
  __shared__ float Wmax[4];
  const int h = blockIdx.x;
  const int t = threadIdx.x;
  const int wave = t >> 6, lane = t & 63;
  const float ib = Wi_b[h];
  const float fb = Wf_b[h];
  const int base = h*SEQ + t*8;

  float it[8], ft[8];
  *(float4*)&it[0] = *(const float4*)&g_itacc[base];
  *(float4*)&it[4] = *(const float4*)&g_itacc[base+4];
  *(float4*)&ft[0] = *(const float4*)&g_ftacc[base];
  *(float4*)&ft[4] = *(const float4*)&g_ftacc[base+4];

  float cs[8];
  float run = 0.f;
  #pragma unroll
  for (int j = 0; j < 8; ++j) {
    const float f = ft[j] + fb;
    const float ls = fminf(f, 0.f) - log1pf(expf(-fabsf(f)));  // logsigmoid
    run += ls;
    cs[j] = run;
  }
  float x = run;
  #pragma unroll
  for (int off = 1; off < 64; off <<= 1) {
    const float tv = __shfl_up(x, off, 64);
    if (lane >= off) x += tv;
  }
  const float wexcl = x - run;
  if (lane == 63) Wsum[wave] = x;
  __syncthreads();
  float boff = 0.f;
  #pragma unroll
  for (int w = 0; w < 4; ++w) if (w < wave) boff += Wsum[w];
  const float cbase = boff + wexcl;

  float a[8], am[8], csum[8];
  float m = -__builtin_inff();
  #pragma unroll
  for (int j = 0; j < 8; ++j) {
    csum[j] = cbase + cs[j];
    a[j] = (it[j] + ib) - csum[j];
    m = fmaxf(m, a[j]);
    am[j] = m;
  }
  float y = m;
  #pragma unroll
  for (int off = 1; off < 64; off <<= 1) {
    const float tv = __shfl_up(y, off, 64);
    if (lane >= off) y = fmaxf(y, tv);
  }
  float e = __shfl_up(y, 1, 64);
  if (lane == 0) e = -__builtin_inff();
  if (lane == 63) Wmax[wave] = y;
  __syncthreads();
  float bmax = -__builtin_inff();
  #pragma unroll
  for (int w = 0; w < 4; ++w) if (w < wave) bmax = fmaxf(bmax, Wmax[w]);
  const float pre = fmaxf(bmax, e);

  float oa[8], ocm[8], oen[8];
  #pragma unroll
  for (int j = 0; j < 8; ++j) {
    const float cm = fmaxf(pre, am[j]);
    oa[j]  = a[j] * LOG2E;
    ocm[j] = cm * LOG2E;
    oen[j] = expf(-(csum[j] + cm));
  }
  *(float4*)&g_aL[base]    = *(float4*)&oa[0];
  *(float4*)&g_aL[base+4]  = *(float4*)&oa[4];
  *(float4*)&g_cmL[base]   = *(float4*)&ocm[0];
  *(float4*)&g_cmL[base+4] = *(float4*)&ocm[4];
  *(float4*)&g_en[base]    = *(float4*)&oen[0];
  *(float4*)&g_en[base+4]  = *(float4*)&oen[4];
}

// ------- kernel 5: j-chunked decay attention, writes fp32 partials -------
// grid = (8 heads, 80 chunk-slots). Slot y -> (iT, c): group g = iT>>3 has
// g+1 chunks of <=8 j-tiles. Q A-frags live in registers (no Qs LDS buffer);
// next K/Vt tile prefetched into registers while computing the current one.
__global__ __launch_bounds__(256, 2) void attn1_kernel() {
  __shared__ __align__(16) unsigned short Ks[64*136];
  __shared__ __align__(16) unsigned short Ps[64*72];
  __shared__ __align__(16) unsigned short Vt[128*72];   // V^T tile: [d][j]
  __shared__ float Sred[64][2];

  const int h = blockIdx.x;
  const int y = blockIdx.y;
  // decode slot -> (iT, chunk)
  int g, s0g;
  if      (y < 8)  { g = 0; s0g = 0;  }
  else if (y < 24) { g = 1; s0g = 8;  }
  else if (y < 48) { g = 2; s0g = 24; }
  else             { g = 3; s0g = 48; }
  const int rel = y - s0g;
  const int iT  = 8*g + rel/(g+1);
  const int ch  = rel - (rel/(g+1))*(g+1);
  const int slot = h*80 + y;
  const int i0 = iT*64;
  const int jt0 = ch*8;
  const int jt1 = (jt0 + 8 < iT + 1) ? (jt0 + 8) : (iT + 1);

  const int tid = threadIdx.x;
  const int wave = tid >> 6;
  const int lane = tid & 63;
  const int q4 = lane >> 4;
  const int l16 = lane & 15;
  const int wr = wave >> 1;
  const int wc = wave & 1;

  // Q A-fragments: registers for the whole block (rows i0+32*wr+16*tr+l16)
  bf16x8 qa[2][4];
  {
    const unsigned short* Qg = g_Qb + (h*SEQ + i0 + 32*wr + l16)*HD;
    #pragma unroll
    for (int tr = 0; tr < 2; ++tr)
      #pragma unroll
      for (int ks = 0; ks < 4; ++ks)
        qa[tr][ks] = *(const bf16x8*)&Qg[tr*16*HD + ks*32 + q4*8];
  }

  float cmv[2][4];
  #pragma unroll
  for (int tr = 0; tr < 2; ++tr)
    #pragma unroll
    for (int r = 0; r < 4; ++r)
      cmv[tr][r] = g_cmL[h*SEQ + i0 + 32*wr + 16*tr + 4*q4 + r];

  f32x4 accH[2][4];
  float rs[2][4];
  const f32x4 fzero = {0.f, 0.f, 0.f, 0.f};
  #pragma unroll
  for (int tr = 0; tr < 2; ++tr) {
    #pragma unroll
    for (int tc = 0; tc < 4; ++tc) accH[tr][tc] = fzero;
    #pragma unroll
    for (int r = 0; r < 4; ++r) rs[tr][r] = 0.f;
  }

  // staging geometry
  const int r0 = tid >> 4;            // K: rows r0, r0+16, r0+32, r0+48
  const int c8 = (tid & 15) * 8;      // K: 8-col chunk
  const int dK = tid >> 1;            // Vt: d-row
  const int cV = (tid & 1) * 32;      // Vt: 32-j half

  const unsigned short* Kgh = g_Kb + h*SEQ*HD;
  const unsigned short* Vgh = g_Vt + h*HD*SEQ;

  us8 Kr[4], Vr[4];
  { // prefetch first tile
    const unsigned short* kp = Kgh + jt0*64*HD;
    const unsigned short* vp = Vgh + jt0*64;
    #pragma unroll
    for (int i = 0; i < 4; ++i) Kr[i] = *(const us8*)&kp[(r0 + 16*i)*HD + c8];
    #pragma unroll
    for (int j = 0; j < 4; ++j) Vr[j] = *(const us8*)&vp[dK*SEQ + cV + 8*j];
  }

  for (int jt = jt0; jt < jt1; ++jt) {
    const int j0 = jt*64;
    __syncthreads();  // previous iter's Ks/Vt/Ps reads complete
    #pragma unroll
    for (int i = 0; i < 4; ++i) *(us8*)&Ks[(r0 + 16*i)*136 + c8] = Kr[i];
    #pragma unroll
    for (int j = 0; j < 4; ++j) *(us8*)&Vt[dK*72 + cV + 8*j] = Vr[j];
    float aLv[2];
    aLv[0] = g_aL[h*SEQ + j0 + 32*wc + l16];
    aLv[1] = g_aL[h*SEQ + j0 + 32*wc + 16 + l16];
    __syncthreads();

    if (jt + 1 < jt1) { // prefetch next tile; latency hidden behind QK/P/PV
      const unsigned short* kp = Kgh + (j0 + 64)*HD;
      const unsigned short* vp = Vgh + (j0 + 64);
      #pragma unroll
      for (int i = 0; i < 4; ++i) Kr[i] = *(const us8*)&kp[(r0 + 16*i)*HD + c8];
      #pragma unroll
      for (int j = 0; j < 4; ++j) Vr[j] = *(const us8*)&vp[dK*SEQ + cV + 8*j];
    }

    // QK^T
    f32x4 c00 = fzero, c01 = fzero, c10 = fzero, c11 = fzero;
    #pragma unroll
    for (int ks = 0; ks < 4; ++ks) {
      const int ko = ks*32 + q4*8;
      const bf16x8 b0 = *(const bf16x8*)&Ks[(32*wc      + l16)*136 + ko];
      const bf16x8 b1 = *(const bf16x8*)&Ks[(32*wc + 16 + l16)*136 + ko];
      c00 = __builtin_amdgcn_mfma_f32_16x16x32_bf16(qa[0][ks], b0, c00, 0, 0, 0);
      c01 = __builtin_amdgcn_mfma_f32_16x16x32_bf16(qa[0][ks], b1, c01, 0, 0, 0);
      c10 = __builtin_amdgcn_mfma_f32_16x16x32_bf16(qa[1][ks], b0, c10, 0, 0, 0);
      c11 = __builtin_amdgcn_mfma_f32_16x16x32_bf16(qa[1][ks], b1, c11, 0, 0, 0);
    }

    // P = (dot/TAU) * exp2(aL_j - cmL_i), causal mask on diagonal tile
    const bool diag = (jt == iT);
    #pragma unroll
    for (int tr = 0; tr < 2; ++tr) {
      #pragma unroll
      for (int tc = 0; tc < 2; ++tc) {
        const f32x4 cc = tr ? (tc ? c11 : c10) : (tc ? c01 : c00);
        const int jg = j0 + 32*wc + 16*tc + l16;
        #pragma unroll
        for (int r = 0; r < 4; ++r) {
          const int rloc = 32*wr + 16*tr + 4*q4 + r;
          const int ig = i0 + rloc;
          const float w = exp2f(aLv[tc] - cmv[tr][r]) * INVTAU;
          float p = cc[r] * w;
          if (diag && (jg > ig)) p = 0.f;
          rs[tr][r] += p;
          Ps[rloc*72 + 32*wc + 16*tc + l16] = f2bf(p);
        }
      }
    }
    __syncthreads();  // Ps complete before PV

    // PV: A = Ps rows, B = Vt rows (= V columns)
    #pragma unroll
    for (int ks = 0; ks < 2; ++ks) {
      const int ko = ks*32 + q4*8;
      const bf16x8 p0 = *(const bf16x8*)&Ps[(32*wr      + l16)*72 + ko];
      const bf16x8 p1 = *(const bf16x8*)&Ps[(32*wr + 16 + l16)*72 + ko];
      #pragma unroll
      for (int tc = 0; tc < 4; ++tc) {
        const bf16x8 vb = *(const bf16x8*)&Vt[(64*wc + 16*tc + l16)*72 + ko];
        accH[0][tc] = __builtin_amdgcn_mfma_f32_16x16x32_bf16(p0, vb, accH[0][tc], 0, 0, 0);
        accH[1][tc] = __builtin_amdgcn_mfma_f32_16x16x32_bf16(p1, vb, accH[1][tc], 0, 0, 0);
      }
    }
  }

  // rowsum reduce across 16 column-lanes; combine wc halves via LDS
  #pragma unroll
  for (int tr = 0; tr < 2; ++tr)
    #pragma unroll
    for (int r = 0; r < 4; ++r) {
      float t = rs[tr][r];
      t += __shfl_xor(t, 1, 16);
      t += __shfl_xor(t, 2, 16);
      t += __shfl_xor(t, 4, 16);
      t += __shfl_xor(t, 8, 16);
      rs[tr][r] = t;
    }
  if (l16 == 0) {
    #pragma unroll
    for (int tr = 0; tr < 2; ++tr)
      #pragma unroll
      for (int r = 0; r < 4; ++r)
        Sred[32*wr + 16*tr + 4*q4 + r][wc] = rs[tr][r];
  }
  __syncthreads();

  if (tid < 64) g_Spart[slot*64 + tid] = Sred[tid][0] + Sred[tid][1];

  float* Ob = g_Opart + slot*(64*128);
  #pragma unroll
  for (int tr = 0; tr < 2; ++tr)
    #pragma unroll
    for (int r = 0; r < 4; ++r) {
      const int rloc = 32*wr + 16*tr + 4*q4 + r;
      #pragma unroll
      for (int tc = 0; tc < 4; ++tc)
        Ob[rloc*128 + 64*wc + 16*tc + l16] = accH[tr][tc][r];
    }
}

// ------- kernel 6: reduce partials + maxit normalize + GroupNorm -------
// grid = (8 heads, 32 i-tiles), 256 threads: thread -> (row = t>>2, quarter = t&3)
__global__ __launch_bounds__(256) void reduce_kernel(const float* __restrict__ gnw,
                                                     const float* __restrict__ gnb,
                                                     float* __restrict__ out) {
  const int h  = blockIdx.x;
  const int iT = blockIdx.y;
  const int t  = threadIdx.x;
  const int r  = t >> 2;
  const int qd = t & 3;
  const int qq = iT >> 3;
  const int nch = qq + 1;
  const int slot0 = h*80 + iT + 4*qq*(qq-1) + qq*(iT & 7);

  float acc[32];
  #pragma unroll
  for (int e = 0; e < 32; ++e) acc[e] = 0.f;
  float S = 0.f;
  for (int c = 0; c < nch; ++c) {
    const float* Ob = g_Opart + (slot0 + c)*(64*128) + r*128 + qd*32;
    #pragma unroll
    for (int kk = 0; kk < 8; ++kk) {
      const float4 f = *(const float4*)&Ob[kk*4];
      acc[kk*4+0] += f.x; acc[kk*4+1] += f.y; acc[kk*4+2] += f.z; acc[kk*4+3] += f.w;
    }
    S += g_Spart[(slot0 + c)*64 + r];
  }

  const float en = g_en[h*SEQ + iT*64 + r];
  const float sc = 1.f / (fmaxf(fabsf(S), en) + 1e-6f);
  float s1 = 0.f, s2 = 0.f;
  #pragma unroll
  for (int e = 0; e < 32; ++e) {
    const float xv = acc[e] * sc;
    acc[e] = xv;
    s1 += xv;
    s2 += xv * xv;
  }
  s1 += __shfl_xor(s1, 1, 4); s2 += __shfl_xor(s2, 1, 4);
  s1 += __shfl_xor(s1, 2, 4); s2 += __shfl_xor(s2, 2, 4);
  const float mean = s1 * (1.f/128.f);
  const float var  = s2 * (1.f/128.f) - mean*mean;
  const float rstd = rsqrtf(var + 1e-5f);

  const float* gw = gnw + h*HD + qd*32;
  const float* gb = gnb + h*HD + qd*32;
  float* op = out + (iT*64 + r)*DIMF + h*HD + qd*32;
  #pragma unroll
  for (int kk = 0; kk < 8; ++kk) {
    const float4 w4 = *(const float4*)&gw[kk*4];
    const float4 b4 = *(const float4*)&gb[kk*4];
    float4 o;
    o.x = (acc[kk*4+0] - mean) * rstd * w4.x + b4.x;
    o.y = (acc[kk*4+1] - mean) * rstd * w4.y + b4.y;
    o.z = (acc[kk*4+2] - mean) * rstd * w4.z + b4.z;
    o.w = (acc[kk*4+3] - mean) * rstd * w4.w + b4.w;
    *(float4*)&op[kk*4] = o;
  }
}

extern "C" void kernel_launch(void* const* d_in, const int* in_sizes, int n_in,
                              void* d_out, int out_size, void* d_ws, size_t ws_size,
                              hipStream_t stream) {
  (void)in_sizes; (void)n_in; (void)out_size; (void)d_ws; (void)ws_size;
  const float* q    = (const float*)d_in[0];
  const float* k    = (const float*)d_in[1];
  const float* v    = (const float*)d_in[2];
  const float* Wi_w = (const float*)d_in[3];
  const float* Wi_b = (const float*)d_in[4];
  const float* Wf_w = (const float*)d_in[5];
  const float* Wf_b = (const float*)d_in[6];
  const float* gnw  = (const float*)d_in[7];
  const float* gnb  = (const float*)d_in[8];
  float* out = (float*)d_out;

  convert_kernel<<<dim3(6192), 256, 0, stream>>>(q, k, v, Wi_w, Wf_w);
  vtrans_kernel<<<dim3(NH, SEQ/64, HD/64), 256, 0, stream>>>();
  gates_kernel<<<dim3(128), 256, 0, stream>>>();
  scan_kernel<<<dim3(NH), 256, 0, stream>>>(Wi_b, Wf_b);
  attn1_kernel<<<dim3(NH, 80), 256, 0, stream>>>();
  reduce_kernel<<<dim3(NH, SEQ/64), 256, 0, stream>>>(gnw, gnb, out);
}